// Round 9
// baseline (148.226 us; speedup 1.0000x reference)
//
#include <hip/hip_runtime.h>

// =====================================================================
// VeroneseDecoding: out[:, 0:4] = top-eigenvector(sym4x4(z[:, :10])) (sign-fixed)
//                   out[:, 4:132] = relu(z @ W1 + b1) @ W2 + b2
// Inputs (f32): z[65536,256], W1[256,1024], b1[1024], W2[1024,128], b2[128]
// Output (f32): [65536,132]
// R9: ZERO-LDS / ZERO-BARRIER design. W1^T/W2^T are L2-resident (768 KB,
// fragment-major); every MFMA operand is read directly from L2 as a
// per-lane coalesced global_load_dwordx4. No staging, no __syncthreads,
// no vmcnt(0) drains -- pure dataflow loop; 1-wave blocks (grid 2048)
// desync freely and hide each other's L2 latency. h stays in-register
// (cvt_pk + permlane32_swap). 32x32x16 MFMA.
// =====================================================================

typedef short s16x8 __attribute__((ext_vector_type(8)));   // 8 bf16 (4 VGPRs)
typedef float f32x4 __attribute__((ext_vector_type(4)));
typedef float f32x16 __attribute__((ext_vector_type(16)));
typedef unsigned char u8;

__device__ __forceinline__ f32x16 mfma32(s16x8 a, s16x8 b, f32x16 c) {
    return __builtin_amdgcn_mfma_f32_32x32x16_bf16(a, b, c, 0, 0, 0);
}

// manual RNE f32 -> bf16 bits (prep kernel only; off critical path)
__device__ __forceinline__ short f2bf(float f) {
    unsigned int u = __float_as_uint(f);
    u = (u + 0x7fffu + ((u >> 16) & 1u)) >> 16;
    return (short)u;
}

// packed RNE convert: 2 f32 -> 1 dword of 2 bf16
__device__ __forceinline__ unsigned cvt_pk(float lo, float hi) {
    unsigned r;
    asm("v_cvt_pk_bf16_f32 %0, %1, %2" : "=v"(r) : "v"(lo), "v"(hi));
    return r;
}

// v_permlane32_swap_b32: a' = [a.lo, b.lo], b' = [a.hi, b.hi]
__device__ __forceinline__ void pl32swap(unsigned& a, unsigned& b) {
    asm("v_permlane32_swap_b32 %0, %1" : "+v"(a), "+v"(b));
}

// ---------------------------------------------------------------------
// prep: W1^T / W2^T -> bf16 fragment-major for 32x32x16 MFMA.
//   w1t unit f = c*2048 + ct*1024 + s*64 + lane   (c<16, ct<2, s<16)
//     lane l holds W1[k = s*16 + (l>>5)*8 + j][n1 = c*64 + ct*32 + (l&31)]
//   w2t unit f = K*256 + nt*64 + lane             (K<64, nt<4)
//     lane l holds W2[k2 = K*16 + (l>>5)*8 + j][n2 = nt*32 + (l&31)]
// ---------------------------------------------------------------------
__global__ __launch_bounds__(256) void prep_weights(
    const float* __restrict__ W1, const float* __restrict__ W2,
    uint4* __restrict__ w1t, uint4* __restrict__ w2t)
{
    int tid = blockIdx.x * 256 + threadIdx.x;
    int hl = (tid >> 5) & 1, r32 = tid & 31;
    union { short b[8]; uint4 v; } pk;
    if (tid < 32768) {                       // 32768 units = 512KB
        int s  = (tid >> 6) & 15;
        int ct = (tid >> 10) & 1;
        int c  = tid >> 11;
        int k0 = s * 16 + hl * 8;
        int n1 = c * 64 + ct * 32 + r32;
        #pragma unroll
        for (int j = 0; j < 8; ++j)
            pk.b[j] = f2bf(W1[(k0 + j) * 1024 + n1]);
        w1t[tid] = pk.v;
    } else {                                 // 16384 units = 256KB
        int g  = tid - 32768;
        int nt = (g >> 6) & 3;
        int K  = g >> 8;
        int k0 = K * 16 + hl * 8;
        int n2 = nt * 32 + r32;
        #pragma unroll
        for (int j = 0; j < 8; ++j)
            pk.b[j] = f2bf(W2[(k0 + j) * 128 + n2]);
        w2t[g] = pk.v;
    }
}

// ---------------------------------------------------------------------
// fused kernel: 1 wave per block, 32 rows per wave, grid 2048.
// No LDS, no barriers. All weight fragments streamed from L2.
// ---------------------------------------------------------------------
__global__ __launch_bounds__(64, 2) void fused_all(
    const float* __restrict__ z, const float* __restrict__ b1,
    const float* __restrict__ b2, const uint4* __restrict__ w1t,
    const uint4* __restrict__ w2t, float* __restrict__ out)
{
    const int lane = threadIdx.x & 63;
    const int hl   = lane >> 5;     // half-wave 0/1
    const int r32  = lane & 31;
    const int rowbase = blockIdx.x * 32;

    // ---------------- eig (lanes 0..31: this wave's 32 rows) ------------
    if (lane < 32) {
        int row = rowbase + lane;
        const float* zr = z + (size_t)row * 256;
        float4 v0 = *(const float4*)(zr);
        float4 v1 = *(const float4*)(zr + 4);
        float2 v2 = *(const float2*)(zr + 8);

        float A[4][4] = {{v0.x, v0.y, v0.z, v0.w},
                         {v0.y, v1.x, v1.y, v1.z},
                         {v0.z, v1.y, v1.w, v2.x},
                         {v0.w, v1.z, v2.x, v2.y}};
        float V[4][4] = {{1.f, 0.f, 0.f, 0.f},
                         {0.f, 1.f, 0.f, 0.f},
                         {0.f, 0.f, 1.f, 0.f},
                         {0.f, 0.f, 0.f, 1.f}};

#define ROT(p, qq) do {                                                   \
        float apq  = A[p][qq];                                            \
        float tau  = (A[qq][qq] - A[p][p]) *                              \
                     __builtin_amdgcn_rcpf(2.0f * apq);                   \
        float tt   = __builtin_amdgcn_rcpf(                               \
                        fabsf(tau) +                                      \
                        __builtin_amdgcn_sqrtf(fmaf(tau, tau, 1.0f)));    \
        tt = copysignf(tt, tau);                                          \
        tt = (fabsf(apq) > 1e-20f) ? tt : 0.0f;                           \
        float cth = __builtin_amdgcn_rsqf(fmaf(tt, tt, 1.0f));            \
        float sth = tt * cth;                                             \
        _Pragma("unroll")                                                 \
        for (int k = 0; k < 4; ++k) {                                     \
            float akp = A[k][p], akq = A[k][qq];                          \
            A[k][p]  = cth * akp - sth * akq;                             \
            A[k][qq] = sth * akp + cth * akq;                             \
        }                                                                 \
        _Pragma("unroll")                                                 \
        for (int k = 0; k < 4; ++k) {                                     \
            float apk = A[p][k], aqk = A[qq][k];                          \
            A[p][k]  = cth * apk - sth * aqk;                             \
            A[qq][k] = sth * apk + cth * aqk;                             \
        }                                                                 \
        _Pragma("unroll")                                                 \
        for (int k = 0; k < 4; ++k) {                                     \
            float vkp = V[k][p], vkq = V[k][qq];                          \
            V[k][p]  = cth * vkp - sth * vkq;                             \
            V[k][qq] = sth * vkp + cth * vkq;                             \
        }                                                                 \
    } while (0)

        #pragma unroll 1
        for (int sweep = 0; sweep < 6; ++sweep) {
            ROT(0, 1); ROT(0, 2); ROT(0, 3); ROT(1, 2); ROT(1, 3); ROT(2, 3);
        }
#undef ROT

        float bv = A[0][0];
        float q0 = V[0][0], q1 = V[1][0], q2 = V[2][0], q3 = V[3][0];
        #pragma unroll
        for (int k = 1; k < 4; ++k) {
            bool better = A[k][k] > bv;
            bv = better ? A[k][k] : bv;
            q0 = better ? V[0][k] : q0;
            q1 = better ? V[1][k] : q1;
            q2 = better ? V[2][k] : q2;
            q3 = better ? V[3][k] : q3;
        }
        float sgn = (q0 + 1e-9f) >= 0.0f ? 1.0f : -1.0f;
        *(float4*)(out + (size_t)row * 132) =
            make_float4(sgn * q0, sgn * q1, sgn * q2, sgn * q3);
    }

    // ---------------- persistent z B-fragments (32x32 layout) ----------
    // zf[s]: lane l holds z[rowbase + (l&31)][s*16 + (l>>5)*8 + j], j=0..7
    s16x8 zf[16];
    {
        const float* zp = z + (size_t)(rowbase + r32) * 256 + hl * 8;
        #pragma unroll
        for (int s = 0; s < 16; ++s) {
            float4 a0 = *(const float4*)(zp + s * 16);
            float4 a1 = *(const float4*)(zp + s * 16 + 4);
            union { unsigned u[4]; s16x8 v; } pk;
            pk.u[0] = cvt_pk(a0.x, a0.y);
            pk.u[1] = cvt_pk(a0.z, a0.w);
            pk.u[2] = cvt_pk(a1.x, a1.y);
            pk.u[3] = cvt_pk(a1.z, a1.w);
            zf[s] = pk.v;
        }
    }

    const f32x16 zero16 = {0.f,0.f,0.f,0.f, 0.f,0.f,0.f,0.f,
                           0.f,0.f,0.f,0.f, 0.f,0.f,0.f,0.f};
    f32x16 acc2[4];
    #pragma unroll
    for (int nt = 0; nt < 4; ++nt) acc2[nt] = zero16;

    const s16x8* const w1b = (const s16x8*)w1t + lane;
    const s16x8* const w2b = (const s16x8*)w2t + lane;
    const float* const bbp = b1 + hl * 4;

    s16x8 hf[4];       // h fragments of the current chunk (registers only)

    // pack one GEMM1 D-tile -> 2 h fragments (bias+relu+cvt_pk+permlane)
    auto pack = [&](const f32x16& d, int c, int ct, s16x8* hfo) {
        unsigned Plo[4], Phi[4];
        #pragma unroll
        for (int g = 0; g < 4; ++g) {
            f32x4 bv = *(const f32x4*)(bbp + c * 64 + ct * 32 + g * 8);
            Plo[g] = cvt_pk(fmaxf(d[4*g+0] + bv[0], 0.f),
                            fmaxf(d[4*g+1] + bv[1], 0.f));
            Phi[g] = cvt_pk(fmaxf(d[4*g+2] + bv[2], 0.f),
                            fmaxf(d[4*g+3] + bv[3], 0.f));
        }
        #pragma unroll
        for (int f = 0; f < 2; ++f) {
            unsigned a0 = Plo[2*f], b0 = Plo[2*f+1];
            unsigned a1 = Phi[2*f], b1_ = Phi[2*f+1];
            pl32swap(a0, b0);
            pl32swap(a1, b1_);
            union { unsigned u[4]; s16x8 v; } fr;
            fr.u[0] = a0; fr.u[1] = a1; fr.u[2] = b0; fr.u[3] = b1_;
            hfo[f] = fr.v;
        }
    };

    // ---------------- main loop: pure dataflow, no sync ------------------
    #pragma unroll 2
    for (int c = 0; c < 16; ++c) {
        const s16x8* w1c = w1b + c * 2048;
        #pragma unroll
        for (int ct = 0; ct < 2; ++ct) {
            f32x16 d = zero16;
            __builtin_amdgcn_s_setprio(1);
            #pragma unroll
            for (int s = 0; s < 16; ++s)
                d = mfma32(w1c[(ct * 16 + s) * 64], zf[s], d);
            __builtin_amdgcn_s_setprio(0);
            pack(d, c, ct, hf + 2 * ct);
        }
        const s16x8* w2c = w2b + c * 1024;
        __builtin_amdgcn_s_setprio(1);
        #pragma unroll
        for (int ks = 0; ks < 4; ++ks)
            #pragma unroll
            for (int nt = 0; nt < 4; ++nt)
                acc2[nt] = mfma32(hf[ks], w2c[(ks * 4 + nt) * 64], acc2[nt]);
        __builtin_amdgcn_s_setprio(0);
    }

    // ---- epilogue: out[m][4 + n2] = acc2 + b2 ----
    #pragma unroll
    for (int nt = 0; nt < 4; ++nt) {
        const float b2v = b2[nt * 32 + r32];
        #pragma unroll
        for (int r = 0; r < 16; ++r) {
            int m = (r & 3) + 8 * (r >> 2) + 4 * hl;
            out[(size_t)(rowbase + m) * 132 + 4 + nt * 32 + r32] =
                acc2[nt][r] + b2v;
        }
    }
}

// ---------------------------------------------------------------------
extern "C" void kernel_launch(void* const* d_in, const int* in_sizes, int n_in,
                              void* d_out, int out_size, void* d_ws, size_t ws_size,
                              hipStream_t stream) {
    const float* z  = (const float*)d_in[0];
    const float* W1 = (const float*)d_in[1];
    const float* b1 = (const float*)d_in[2];
    const float* W2 = (const float*)d_in[3];
    const float* b2 = (const float*)d_in[4];
    float* out = (float*)d_out;

    // ws layout: [0, 512KB) W1^T frag-major, [512KB, 768KB) W2^T frag-major
    uint4* w1t = (uint4*)d_ws;
    uint4* w2t = (uint4*)((char*)d_ws + 512 * 1024);

    hipLaunchKernelGGL(prep_weights, dim3(192), dim3(256), 0, stream,
                       W1, W2, w1t, w2t);
    hipLaunchKernelGGL(fused_all, dim3(2048), dim3(64), 0, stream,
                       z, b1, b2, (const uint4*)w1t, (const uint4*)w2t, out);
}

// Round 10
// 75.015 us; speedup vs baseline: 1.9760x; 1.9760x over previous
//
#include <hip/hip_runtime.h>

// =====================================================================
// VeroneseDecoding: out[:, 0:4] = top-eigenvector(sym4x4(z[:, :10])) (sign-fixed)
//                   out[:, 4:132] = relu(z @ W1 + b1) @ W2 + b2
// Inputs (f32): z[65536,256], W1[256,1024], b1[1024], W2[1024,128], b2[128]
// Output (f32): [65536,132]
// R10: R6 structure + counted-vmcnt barriers (T4). Per chunk:
//   s_waitcnt vmcnt(16); raw s_barrier; issue stage(c+1); GEMM1; GEMM2.
// Next-chunk gload_lds prefetch stays IN FLIGHT across the barrier
// (no vmcnt(0) drain). 32x32x16 MFMA, h in-register (cvt_pk+permlane),
// W1 LDS dbuf, W2 frags from L2. BM=128, 4 waves, grid 512, 2 blk/CU.
// =====================================================================

typedef short s16x8 __attribute__((ext_vector_type(8)));   // 8 bf16 (4 VGPRs)
typedef float f32x4 __attribute__((ext_vector_type(4)));
typedef float f32x16 __attribute__((ext_vector_type(16)));
typedef unsigned char u8;

__device__ __forceinline__ f32x16 mfma32(s16x8 a, s16x8 b, f32x16 c) {
    return __builtin_amdgcn_mfma_f32_32x32x16_bf16(a, b, c, 0, 0, 0);
}

// manual RNE f32 -> bf16 bits (prep kernel only; off critical path)
__device__ __forceinline__ short f2bf(float f) {
    unsigned int u = __float_as_uint(f);
    u = (u + 0x7fffu + ((u >> 16) & 1u)) >> 16;
    return (short)u;
}

// packed RNE convert: 2 f32 -> 1 dword of 2 bf16
__device__ __forceinline__ unsigned cvt_pk(float lo, float hi) {
    unsigned r;
    asm("v_cvt_pk_bf16_f32 %0, %1, %2" : "=v"(r) : "v"(lo), "v"(hi));
    return r;
}

// v_permlane32_swap_b32: a' = [a.lo, b.lo], b' = [a.hi, b.hi]
__device__ __forceinline__ void pl32swap(unsigned& a, unsigned& b) {
    asm("v_permlane32_swap_b32 %0, %1" : "+v"(a), "+v"(b));
}

// async global->LDS, 16B per lane. Dest must be wave-uniform base + lane*16.
__device__ __forceinline__ void gload_lds16(const void* g, void* l) {
    __builtin_amdgcn_global_load_lds(
        (const __attribute__((address_space(1))) unsigned int*)g,
        (__attribute__((address_space(3))) unsigned int*)l, 16, 0, 0);
}

// ---------------------------------------------------------------------
// prep: W1^T / W2^T -> bf16 fragment-major for 32x32x16 MFMA.
//   w1t unit f = c*2048 + ct*1024 + s*64 + lane   (c<16, ct<2, s<16)
//     lane l holds W1[k = s*16 + (l>>5)*8 + j][n1 = c*64 + ct*32 + (l&31)]
//   w2t unit f = K*256 + nt*64 + lane             (K<64, nt<4)
//     lane l holds W2[k2 = K*16 + (l>>5)*8 + j][n2 = nt*32 + (l&31)]
// ---------------------------------------------------------------------
__global__ __launch_bounds__(256) void prep_weights(
    const float* __restrict__ W1, const float* __restrict__ W2,
    uint4* __restrict__ w1t, uint4* __restrict__ w2t)
{
    int tid = blockIdx.x * 256 + threadIdx.x;
    int hl = (tid >> 5) & 1, r32 = tid & 31;
    union { short b[8]; uint4 v; } pk;
    if (tid < 32768) {                       // 32768 units = 512KB
        int s  = (tid >> 6) & 15;
        int ct = (tid >> 10) & 1;
        int c  = tid >> 11;
        int k0 = s * 16 + hl * 8;
        int n1 = c * 64 + ct * 32 + r32;
        #pragma unroll
        for (int j = 0; j < 8; ++j)
            pk.b[j] = f2bf(W1[(k0 + j) * 1024 + n1]);
        w1t[tid] = pk.v;
    } else {                                 // 16384 units = 256KB
        int g  = tid - 32768;
        int nt = (g >> 6) & 3;
        int K  = g >> 8;
        int k0 = K * 16 + hl * 8;
        int n2 = nt * 32 + r32;
        #pragma unroll
        for (int j = 0; j < 8; ++j)
            pk.b[j] = f2bf(W2[(k0 + j) * 128 + n2]);
        w2t[g] = pk.v;
    }
}

// ---------------------------------------------------------------------
// fused kernel. LDS: bs1 2x32KB (W1 chunk dbuf) + 4KB bias = 68KB.
// ---------------------------------------------------------------------
__global__ __launch_bounds__(256, 2) void fused_all(
    const float* __restrict__ z, const float* __restrict__ b1,
    const float* __restrict__ b2, const uint4* __restrict__ w1t,
    const uint4* __restrict__ w2t, float* __restrict__ out)
{
    __shared__ __align__(16) u8 lds[69632];
    // [0,32768) bs1 buf0 | [32768,65536) bs1 buf1 | [65536,69632) b1 f32

    const int t    = threadIdx.x;
    const int lane = t & 63;
    const int w    = t >> 6;        // wave 0..3
    const int hl   = lane >> 5;     // half-wave 0/1
    const int r32  = lane & 31;
    const int bm0  = blockIdx.x * 128;
    const int rowbase = bm0 + w * 32;

    // ---------------- issue stage of chunk 0 + bias (async) ------------
    #pragma unroll
    for (int i = 0; i < 8; ++i) {
        int f = i * 256 + t;
        gload_lds16(w1t + f, lds + f * 16);
    }
    gload_lds16(b1 + t * 4, lds + 65536 + t * 16);

    // ---------------- eig (lanes 0..31: this wave's 32 rows) ------------
    if (lane < 32) {
        int row = rowbase + lane;
        const float* zr = z + (size_t)row * 256;
        float4 v0 = *(const float4*)(zr);
        float4 v1 = *(const float4*)(zr + 4);
        float2 v2 = *(const float2*)(zr + 8);

        float A[4][4] = {{v0.x, v0.y, v0.z, v0.w},
                         {v0.y, v1.x, v1.y, v1.z},
                         {v0.z, v1.y, v1.w, v2.x},
                         {v0.w, v1.z, v2.x, v2.y}};
        float V[4][4] = {{1.f, 0.f, 0.f, 0.f},
                         {0.f, 1.f, 0.f, 0.f},
                         {0.f, 0.f, 1.f, 0.f},
                         {0.f, 0.f, 0.f, 1.f}};

#define ROT(p, qq) do {                                                   \
        float apq  = A[p][qq];                                            \
        float tau  = (A[qq][qq] - A[p][p]) *                              \
                     __builtin_amdgcn_rcpf(2.0f * apq);                   \
        float tt   = __builtin_amdgcn_rcpf(                               \
                        fabsf(tau) +                                      \
                        __builtin_amdgcn_sqrtf(fmaf(tau, tau, 1.0f)));    \
        tt = copysignf(tt, tau);                                          \
        tt = (fabsf(apq) > 1e-20f) ? tt : 0.0f;                           \
        float cth = __builtin_amdgcn_rsqf(fmaf(tt, tt, 1.0f));            \
        float sth = tt * cth;                                             \
        _Pragma("unroll")                                                 \
        for (int k = 0; k < 4; ++k) {                                     \
            float akp = A[k][p], akq = A[k][qq];                          \
            A[k][p]  = cth * akp - sth * akq;                             \
            A[k][qq] = sth * akp + cth * akq;                             \
        }                                                                 \
        _Pragma("unroll")                                                 \
        for (int k = 0; k < 4; ++k) {                                     \
            float apk = A[p][k], aqk = A[qq][k];                          \
            A[p][k]  = cth * apk - sth * aqk;                             \
            A[qq][k] = sth * apk + cth * aqk;                             \
        }                                                                 \
        _Pragma("unroll")                                                 \
        for (int k = 0; k < 4; ++k) {                                     \
            float vkp = V[k][p], vkq = V[k][qq];                          \
            V[k][p]  = cth * vkp - sth * vkq;                             \
            V[k][qq] = sth * vkp + cth * vkq;                             \
        }                                                                 \
    } while (0)

        #pragma unroll 1
        for (int sweep = 0; sweep < 6; ++sweep) {
            ROT(0, 1); ROT(0, 2); ROT(0, 3); ROT(1, 2); ROT(1, 3); ROT(2, 3);
        }
#undef ROT

        float bv = A[0][0];
        float q0 = V[0][0], q1 = V[1][0], q2 = V[2][0], q3 = V[3][0];
        #pragma unroll
        for (int k = 1; k < 4; ++k) {
            bool better = A[k][k] > bv;
            bv = better ? A[k][k] : bv;
            q0 = better ? V[0][k] : q0;
            q1 = better ? V[1][k] : q1;
            q2 = better ? V[2][k] : q2;
            q3 = better ? V[3][k] : q3;
        }
        float sgn = (q0 + 1e-9f) >= 0.0f ? 1.0f : -1.0f;
        *(float4*)(out + (size_t)row * 132) =
            make_float4(sgn * q0, sgn * q1, sgn * q2, sgn * q3);
    }

    // ---------------- persistent z B-fragments (32x32 layout) ----------
    // zf[s]: lane l holds z[rowbase + (l&31)][s*16 + (l>>5)*8 + j], j=0..7
    s16x8 zf[16];
    {
        const float* zp = z + (size_t)(rowbase + r32) * 256 + hl * 8;
        #pragma unroll
        for (int s = 0; s < 16; ++s) {
            float4 a0 = *(const float4*)(zp + s * 16);
            float4 a1 = *(const float4*)(zp + s * 16 + 4);
            union { unsigned u[4]; s16x8 v; } pk;
            pk.u[0] = cvt_pk(a0.x, a0.y);
            pk.u[1] = cvt_pk(a0.z, a0.w);
            pk.u[2] = cvt_pk(a1.x, a1.y);
            pk.u[3] = cvt_pk(a1.z, a1.w);
            zf[s] = pk.v;
        }
    }

    const f32x16 zero16 = {0.f,0.f,0.f,0.f, 0.f,0.f,0.f,0.f,
                           0.f,0.f,0.f,0.f, 0.f,0.f,0.f,0.f};
    f32x16 acc2[4];
    #pragma unroll
    for (int nt = 0; nt < 4; ++nt) acc2[nt] = zero16;

    __syncthreads();   // prologue full drain: chunk-0 staging + bias landed

    const u8* const aW0  = lds + lane * 16;           // bs1 buf0
    const u8* const aW1  = lds + 32768 + lane * 16;   // bs1 buf1
    const u8* const blsp = lds + 65536 + hl * 16;     // bias (2-way bcast)
    const s16x8* const w2b = (const s16x8*)w2t + lane;

    u8* const s1b0 = lds;
    u8* const s1b1 = lds + 32768;

    // pack one GEMM1 D-tile -> 2 h fragments (bias+relu+cvt_pk+permlane)
    auto pack = [&](const f32x16& d, const u8* bb, int ct, s16x8* hfo) {
        unsigned Plo[4], Phi[4];
        #pragma unroll
        for (int g = 0; g < 4; ++g) {
            f32x4 bv = *(const f32x4*)(bb + ct * 128 + g * 32);
            Plo[g] = cvt_pk(fmaxf(d[4*g+0] + bv[0], 0.f),
                            fmaxf(d[4*g+1] + bv[1], 0.f));
            Phi[g] = cvt_pk(fmaxf(d[4*g+2] + bv[2], 0.f),
                            fmaxf(d[4*g+3] + bv[3], 0.f));
        }
        #pragma unroll
        for (int f = 0; f < 2; ++f) {
            unsigned a0 = Plo[2*f], b0 = Plo[2*f+1];
            unsigned a1 = Phi[2*f], b1_ = Phi[2*f+1];
            pl32swap(a0, b0);
            pl32swap(a1, b1_);
            union { unsigned u[4]; s16x8 v; } fr;
            fr.u[0] = a0; fr.u[1] = a1; fr.u[2] = b0; fr.u[3] = b1_;
            hfo[f] = fr.v;
        }
    };

    // chunk c (FIRST/LAST compile-time at call sites):
    //   counted wait (stage(c) landed; stage(c+1) & W2 stay in flight)
    //   raw barrier; issue stage(c+1); GEMM1 (2 live chains); GEMM2.
    auto chunk = [&](int c, const u8* a, u8* s1dst, bool FIRST, bool LAST) {
        if (!FIRST) {
            // 16 W2 b128 loads were issued after stage(c)'s 8 gload_lds;
            // vmcnt retires in order -> <=16 outstanding == stage(c) landed.
            asm volatile("s_waitcnt vmcnt(16)" ::: "memory");
        }
        __builtin_amdgcn_s_barrier();   // raw: no vmcnt(0) drain

        if (!LAST) {    // stage W1 chunk c+1 into the other buffer
            const uint4* s1 = w1t + (c + 1) * 2048;
            #pragma unroll
            for (int i = 0; i < 8; ++i) {
                int f = i * 256 + t;
                gload_lds16(s1 + f, s1dst + f * 16);
            }
        }

        // ---- issue all 16 W2 fragment loads (L2-hot, used after GEMM1) --
        const s16x8* w2c = w2b + c * 1024;
        s16x8 w2f[4][4];
        #pragma unroll
        for (int ks = 0; ks < 4; ++ks)
            #pragma unroll
            for (int nt = 0; nt < 4; ++nt)
                w2f[ks][nt] = w2c[(ks * 4 + nt) * 64];

        const u8* bb = blsp + c * 256;
        s16x8 hf[4];

        // ---- GEMM1: s-outer, both ct accumulators live (2 indep chains) --
        __builtin_amdgcn_s_setprio(1);
        f32x16 d0 = zero16, d1 = zero16;
        #pragma unroll
        for (int s = 0; s < 16; ++s) {
            s16x8 a0 = *(const s16x8*)(a + s * 1024);
            s16x8 a1 = *(const s16x8*)(a + (16 + s) * 1024);
            d0 = mfma32(a0, zf[s], d0);
            d1 = mfma32(a1, zf[s], d1);
        }
        __builtin_amdgcn_s_setprio(0);

        pack(d0, bb, 0, hf);
        pack(d1, bb, 1, hf + 2);

        // ---- GEMM2: 16 indep accumulator updates ----
        __builtin_amdgcn_s_setprio(1);
        #pragma unroll
        for (int ks = 0; ks < 4; ++ks)
            #pragma unroll
            for (int nt = 0; nt < 4; ++nt)
                acc2[nt] = mfma32(hf[ks], w2f[ks][nt], acc2[nt]);
        __builtin_amdgcn_s_setprio(0);
    };

    chunk(0, aW0, s1b1, true, false);
    #pragma unroll 1
    for (int cc = 0; cc < 7; ++cc) {
        chunk(2 * cc + 1, aW1, s1b0, false, false);
        chunk(2 * cc + 2, aW0, s1b1, false, false);
    }
    chunk(15, aW1, s1b0, false, true);

    // ---- epilogue: out[m][4 + n2] = acc2 + b2 ----
    #pragma unroll
    for (int nt = 0; nt < 4; ++nt) {
        const float b2v = b2[nt * 32 + r32];
        #pragma unroll
        for (int r = 0; r < 16; ++r) {
            int m = (r & 3) + 8 * (r >> 2) + 4 * hl;
            out[(size_t)(bm0 + w * 32 + m) * 132 + 4 + nt * 32 + r32] =
                acc2[nt][r] + b2v;
        }
    }
}

// ---------------------------------------------------------------------
extern "C" void kernel_launch(void* const* d_in, const int* in_sizes, int n_in,
                              void* d_out, int out_size, void* d_ws, size_t ws_size,
                              hipStream_t stream) {
    const float* z  = (const float*)d_in[0];
    const float* W1 = (const float*)d_in[1];
    const float* b1 = (const float*)d_in[2];
    const float* W2 = (const float*)d_in[3];
    const float* b2 = (const float*)d_in[4];
    float* out = (float*)d_out;

    // ws layout: [0, 512KB) W1^T frag-major, [512KB, 768KB) W2^T frag-major
    uint4* w1t = (uint4*)d_ws;
    uint4* w2t = (uint4*)((char*)d_ws + 512 * 1024);

    hipLaunchKernelGGL(prep_weights, dim3(192), dim3(256), 0, stream,
                       W1, W2, w1t, w2t);
    hipLaunchKernelGGL(fused_all, dim3(512), dim3(256), 0, stream,
                       z, b1, b2, (const uint4*)w1t, (const uint4*)w2t, out);
}

// Round 11
// 72.903 us; speedup vs baseline: 2.0332x; 1.0290x over previous
//
#include <hip/hip_runtime.h>

// =====================================================================
// VeroneseDecoding: out[:, 0:4] = top-eigenvector(sym4x4(z[:, :10])) (sign-fixed)
//                   out[:, 4:132] = relu(z @ W1 + b1) @ W2 + b2
// Inputs (f32): z[65536,256], W1[256,1024], b1[1024], W2[1024,128], b2[128]
// Output (f32): [65536,132]
// R11: barrier-sparse grouping to break wave lockstep. One 512-thread
// block/CU (BM=256, 8 waves x 32 rows). W1 staged in 2-chunk GROUPS,
// double-buffered (2x64KB) -> ONE barrier per group (8 total). Waves get
// a ~1400-cy barrier-free window to de-phase so MFMA/LDS/VALU/L2 phases
// of different waves overlap. 32x32x16 MFMA, h in-register
// (cvt_pk+permlane), W2 frags from L2. LDS 132KB, grid 256.
// =====================================================================

typedef short s16x8 __attribute__((ext_vector_type(8)));   // 8 bf16 (4 VGPRs)
typedef float f32x4 __attribute__((ext_vector_type(4)));
typedef float f32x16 __attribute__((ext_vector_type(16)));
typedef unsigned char u8;

__device__ __forceinline__ f32x16 mfma32(s16x8 a, s16x8 b, f32x16 c) {
    return __builtin_amdgcn_mfma_f32_32x32x16_bf16(a, b, c, 0, 0, 0);
}

// manual RNE f32 -> bf16 bits (prep kernel only; off critical path)
__device__ __forceinline__ short f2bf(float f) {
    unsigned int u = __float_as_uint(f);
    u = (u + 0x7fffu + ((u >> 16) & 1u)) >> 16;
    return (short)u;
}

// packed RNE convert: 2 f32 -> 1 dword of 2 bf16
__device__ __forceinline__ unsigned cvt_pk(float lo, float hi) {
    unsigned r;
    asm("v_cvt_pk_bf16_f32 %0, %1, %2" : "=v"(r) : "v"(lo), "v"(hi));
    return r;
}

// v_permlane32_swap_b32: a' = [a.lo, b.lo], b' = [a.hi, b.hi]
__device__ __forceinline__ void pl32swap(unsigned& a, unsigned& b) {
    asm("v_permlane32_swap_b32 %0, %1" : "+v"(a), "+v"(b));
}

// async global->LDS, 16B per lane. Dest must be wave-uniform base + lane*16.
__device__ __forceinline__ void gload_lds16(const void* g, void* l) {
    __builtin_amdgcn_global_load_lds(
        (const __attribute__((address_space(1))) unsigned int*)g,
        (__attribute__((address_space(3))) unsigned int*)l, 16, 0, 0);
}

// ---------------------------------------------------------------------
// prep: W1^T / W2^T -> bf16 fragment-major for 32x32x16 MFMA.
//   w1t unit f = c*2048 + ct*1024 + s*64 + lane   (c<16, ct<2, s<16)
//     lane l holds W1[k = s*16 + (l>>5)*8 + j][n1 = c*64 + ct*32 + (l&31)]
//   w2t unit f = K*256 + nt*64 + lane             (K<64, nt<4)
//     lane l holds W2[k2 = K*16 + (l>>5)*8 + j][n2 = nt*32 + (l&31)]
// ---------------------------------------------------------------------
__global__ __launch_bounds__(256) void prep_weights(
    const float* __restrict__ W1, const float* __restrict__ W2,
    uint4* __restrict__ w1t, uint4* __restrict__ w2t)
{
    int tid = blockIdx.x * 256 + threadIdx.x;
    int hl = (tid >> 5) & 1, r32 = tid & 31;
    union { short b[8]; uint4 v; } pk;
    if (tid < 32768) {                       // 32768 units = 512KB
        int s  = (tid >> 6) & 15;
        int ct = (tid >> 10) & 1;
        int c  = tid >> 11;
        int k0 = s * 16 + hl * 8;
        int n1 = c * 64 + ct * 32 + r32;
        #pragma unroll
        for (int j = 0; j < 8; ++j)
            pk.b[j] = f2bf(W1[(k0 + j) * 1024 + n1]);
        w1t[tid] = pk.v;
    } else {                                 // 16384 units = 256KB
        int g  = tid - 32768;
        int nt = (g >> 6) & 3;
        int K  = g >> 8;
        int k0 = K * 16 + hl * 8;
        int n2 = nt * 32 + r32;
        #pragma unroll
        for (int j = 0; j < 8; ++j)
            pk.b[j] = f2bf(W2[(k0 + j) * 128 + n2]);
        w2t[g] = pk.v;
    }
}

// ---------------------------------------------------------------------
// fused kernel. LDS: 2 group-buffers x 64KB (2 chunks each) + 4KB bias.
// ---------------------------------------------------------------------
__global__ __launch_bounds__(512, 1) void fused_all(
    const float* __restrict__ z, const float* __restrict__ b1,
    const float* __restrict__ b2, const uint4* __restrict__ w1t,
    const uint4* __restrict__ w2t, float* __restrict__ out)
{
    __shared__ __align__(16) u8 lds[135168];
    // [0,65536) group buf A (2x32KB) | [65536,131072) buf B | [131072,+4K) b1

    const int t    = threadIdx.x;
    const int lane = t & 63;
    const int w    = t >> 6;        // wave 0..7
    const int hl   = lane >> 5;     // half-wave 0/1
    const int r32  = lane & 31;
    const int bm0  = blockIdx.x * 256;
    const int rowbase = bm0 + w * 32;

    // ---------------- issue stage of group 0 (chunks 0,1) + bias --------
    #pragma unroll
    for (int i = 0; i < 8; ++i) {
        int f = i * 512 + t;
        gload_lds16(w1t + f, lds + f * 16);
    }
    if (t < 256) gload_lds16(b1 + t * 4, lds + 131072 + t * 16);

    // ---------------- eig (lanes 0..31: this wave's 32 rows) ------------
    if (lane < 32) {
        int row = rowbase + lane;
        const float* zr = z + (size_t)row * 256;
        float4 v0 = *(const float4*)(zr);
        float4 v1 = *(const float4*)(zr + 4);
        float2 v2 = *(const float2*)(zr + 8);

        float A[4][4] = {{v0.x, v0.y, v0.z, v0.w},
                         {v0.y, v1.x, v1.y, v1.z},
                         {v0.z, v1.y, v1.w, v2.x},
                         {v0.w, v1.z, v2.x, v2.y}};
        float V[4][4] = {{1.f, 0.f, 0.f, 0.f},
                         {0.f, 1.f, 0.f, 0.f},
                         {0.f, 0.f, 1.f, 0.f},
                         {0.f, 0.f, 0.f, 1.f}};

#define ROT(p, qq) do {                                                   \
        float apq  = A[p][qq];                                            \
        float tau  = (A[qq][qq] - A[p][p]) *                              \
                     __builtin_amdgcn_rcpf(2.0f * apq);                   \
        float tt   = __builtin_amdgcn_rcpf(                               \
                        fabsf(tau) +                                      \
                        __builtin_amdgcn_sqrtf(fmaf(tau, tau, 1.0f)));    \
        tt = copysignf(tt, tau);                                          \
        tt = (fabsf(apq) > 1e-20f) ? tt : 0.0f;                           \
        float cth = __builtin_amdgcn_rsqf(fmaf(tt, tt, 1.0f));            \
        float sth = tt * cth;                                             \
        _Pragma("unroll")                                                 \
        for (int k = 0; k < 4; ++k) {                                     \
            float akp = A[k][p], akq = A[k][qq];                          \
            A[k][p]  = cth * akp - sth * akq;                             \
            A[k][qq] = sth * akp + cth * akq;                             \
        }                                                                 \
        _Pragma("unroll")                                                 \
        for (int k = 0; k < 4; ++k) {                                     \
            float apk = A[p][k], aqk = A[qq][k];                          \
            A[p][k]  = cth * apk - sth * aqk;                             \
            A[qq][k] = sth * apk + cth * aqk;                             \
        }                                                                 \
        _Pragma("unroll")                                                 \
        for (int k = 0; k < 4; ++k) {                                     \
            float vkp = V[k][p], vkq = V[k][qq];                          \
            V[k][p]  = cth * vkp - sth * vkq;                             \
            V[k][qq] = sth * vkp + cth * vkq;                             \
        }                                                                 \
    } while (0)

        #pragma unroll 1
        for (int sweep = 0; sweep < 6; ++sweep) {
            ROT(0, 1); ROT(0, 2); ROT(0, 3); ROT(1, 2); ROT(1, 3); ROT(2, 3);
        }
#undef ROT

        float bv = A[0][0];
        float q0 = V[0][0], q1 = V[1][0], q2 = V[2][0], q3 = V[3][0];
        #pragma unroll
        for (int k = 1; k < 4; ++k) {
            bool better = A[k][k] > bv;
            bv = better ? A[k][k] : bv;
            q0 = better ? V[0][k] : q0;
            q1 = better ? V[1][k] : q1;
            q2 = better ? V[2][k] : q2;
            q3 = better ? V[3][k] : q3;
        }
        float sgn = (q0 + 1e-9f) >= 0.0f ? 1.0f : -1.0f;
        *(float4*)(out + (size_t)row * 132) =
            make_float4(sgn * q0, sgn * q1, sgn * q2, sgn * q3);
    }

    // ---------------- persistent z B-fragments (32x32 layout) ----------
    // zf[s]: lane l holds z[rowbase + (l&31)][s*16 + (l>>5)*8 + j], j=0..7
    s16x8 zf[16];
    {
        const float* zp = z + (size_t)(rowbase + r32) * 256 + hl * 8;
        #pragma unroll
        for (int s = 0; s < 16; ++s) {
            float4 a0 = *(const float4*)(zp + s * 16);
            float4 a1 = *(const float4*)(zp + s * 16 + 4);
            union { unsigned u[4]; s16x8 v; } pk;
            pk.u[0] = cvt_pk(a0.x, a0.y);
            pk.u[1] = cvt_pk(a0.z, a0.w);
            pk.u[2] = cvt_pk(a1.x, a1.y);
            pk.u[3] = cvt_pk(a1.z, a1.w);
            zf[s] = pk.v;
        }
    }

    const f32x16 zero16 = {0.f,0.f,0.f,0.f, 0.f,0.f,0.f,0.f,
                           0.f,0.f,0.f,0.f, 0.f,0.f,0.f,0.f};
    f32x16 acc2[4];
    #pragma unroll
    for (int nt = 0; nt < 4; ++nt) acc2[nt] = zero16;

    __syncthreads();   // group-0 staging + bias landed

    // thread-constant LDS base pointers: group buf {A,B} x chunk slot {0,1}
    const u8* const aA0 = lds +          lane * 16;
    const u8* const aA1 = lds + 32768  + lane * 16;
    const u8* const aB0 = lds + 65536  + lane * 16;
    const u8* const aB1 = lds + 98304  + lane * 16;
    u8* const sA = lds;
    u8* const sB = lds + 65536;
    const u8* const blsp = lds + 131072 + hl * 16;    // bias (2-way bcast)
    const s16x8* const w2b = (const s16x8*)w2t + lane;

    // pack one GEMM1 D-tile -> 2 h fragments (bias+relu+cvt_pk+permlane)
    auto pack = [&](const f32x16& d, const u8* bb, int ct, s16x8* hfo) {
        unsigned Plo[4], Phi[4];
        #pragma unroll
        for (int g = 0; g < 4; ++g) {
            f32x4 bv = *(const f32x4*)(bb + ct * 128 + g * 32);
            Plo[g] = cvt_pk(fmaxf(d[4*g+0] + bv[0], 0.f),
                            fmaxf(d[4*g+1] + bv[1], 0.f));
            Phi[g] = cvt_pk(fmaxf(d[4*g+2] + bv[2], 0.f),
                            fmaxf(d[4*g+3] + bv[3], 0.f));
        }
        #pragma unroll
        for (int f = 0; f < 2; ++f) {
            unsigned a0 = Plo[2*f], b0 = Plo[2*f+1];
            unsigned a1 = Phi[2*f], b1_ = Phi[2*f+1];
            pl32swap(a0, b0);
            pl32swap(a1, b1_);
            union { unsigned u[4]; s16x8 v; } fr;
            fr.u[0] = a0; fr.u[1] = a1; fr.u[2] = b0; fr.u[3] = b1_;
            hfo[f] = fr.v;
        }
    };

    // one chunk body: W2 loads, GEMM1 (2 chains), pack, GEMM2. NO barrier.
    auto body = [&](int c, const u8* a) {
        const s16x8* w2c = w2b + c * 1024;
        s16x8 w2f[4][4];
        #pragma unroll
        for (int ks = 0; ks < 4; ++ks)
            #pragma unroll
            for (int nt = 0; nt < 4; ++nt)
                w2f[ks][nt] = w2c[(ks * 4 + nt) * 64];

        const u8* bb = blsp + c * 256;
        s16x8 hf[4];

        __builtin_amdgcn_s_setprio(1);
        f32x16 d0 = zero16, d1 = zero16;
        #pragma unroll
        for (int s = 0; s < 16; ++s) {
            s16x8 a0 = *(const s16x8*)(a + s * 1024);
            s16x8 a1 = *(const s16x8*)(a + (16 + s) * 1024);
            d0 = mfma32(a0, zf[s], d0);
            d1 = mfma32(a1, zf[s], d1);
        }
        __builtin_amdgcn_s_setprio(0);

        pack(d0, bb, 0, hf);
        pack(d1, bb, 1, hf + 2);

        __builtin_amdgcn_s_setprio(1);
        #pragma unroll
        for (int ks = 0; ks < 4; ++ks)
            #pragma unroll
            for (int nt = 0; nt < 4; ++nt)
                acc2[nt] = mfma32(hf[ks], w2f[ks][nt], acc2[nt]);
        __builtin_amdgcn_s_setprio(0);
    };

    // group g covers chunks {2g, 2g+1}; stages group g+1; 1 barrier/group.
    auto group = [&](int g, const u8* a0, const u8* a1, u8* dst, bool LASTG) {
        if (!LASTG) {
            const uint4* s1 = w1t + (2 * g + 2) * 2048;
            #pragma unroll
            for (int i = 0; i < 8; ++i) {
                int f = i * 512 + t;
                gload_lds16(s1 + f, dst + f * 16);
            }
        }
        body(2 * g,     a0);
        body(2 * g + 1, a1);
        __syncthreads();   // group g+1 staged; buf of group g free to reuse
    };

    #pragma unroll 1
    for (int gg = 0; gg < 4; ++gg) {
        group(2 * gg,     aA0, aA1, sB, false);
        group(2 * gg + 1, aB0, aB1, sA, gg == 3);
    }

    // ---- epilogue: out[m][4 + n2] = acc2 + b2 ----
    #pragma unroll
    for (int nt = 0; nt < 4; ++nt) {
        const float b2v = b2[nt * 32 + r32];
        #pragma unroll
        for (int r = 0; r < 16; ++r) {
            int m = (r & 3) + 8 * (r >> 2) + 4 * hl;
            out[(size_t)(rowbase + m) * 132 + 4 + nt * 32 + r32] =
                acc2[nt][r] + b2v;
        }
    }
}

// ---------------------------------------------------------------------
extern "C" void kernel_launch(void* const* d_in, const int* in_sizes, int n_in,
                              void* d_out, int out_size, void* d_ws, size_t ws_size,
                              hipStream_t stream) {
    const float* z  = (const float*)d_in[0];
    const float* W1 = (const float*)d_in[1];
    const float* b1 = (const float*)d_in[2];
    const float* W2 = (const float*)d_in[3];
    const float* b2 = (const float*)d_in[4];
    float* out = (float*)d_out;

    // ws layout: [0, 512KB) W1^T frag-major, [512KB, 768KB) W2^T frag-major
    uint4* w1t = (uint4*)d_ws;
    uint4* w2t = (uint4*)((char*)d_ws + 512 * 1024);

    hipLaunchKernelGGL(prep_weights, dim3(192), dim3(256), 0, stream,
                       W1, W2, w1t, w2t);
    hipLaunchKernelGGL(fused_all, dim3(256), dim3(512), 0, stream,
                       z, b1, b2, (const uint4*)w1t, (const uint4*)w2t, out);
}

// Round 12
// 71.771 us; speedup vs baseline: 2.0653x; 1.0158x over previous
//
#include <hip/hip_runtime.h>

// =====================================================================
// VeroneseDecoding: out[:, 0:4] = top-eigenvector(sym4x4(z[:, :10])) (sign-fixed)
//                   out[:, 4:132] = relu(z @ W1 + b1) @ W2 + b2
// Inputs (f32): z[65536,256], W1[256,1024], b1[1024], W2[1024,128], b2[128]
// Output (f32): [65536,132]
// R12: m201-style multi-phase schedule. Triple-buffered LDS (W1+W2 per
// chunk, prefetch distance 2, vmcnt(6) once per chunk - never 0 in loop).
// 6 phases/chunk: {8 ds_read + gloads | bar | lgkm0 | prio1 | 8 MFMA |
// prio0 | bar}. pack VALU in GEMM2 phase headers. Fully unrolled.
// 512 thr = 8 waves x 32 rows (BM=256), grid 256, LDS 148KB (1 blk/CU).
// =====================================================================

typedef short s16x8 __attribute__((ext_vector_type(8)));   // 8 bf16 (4 VGPRs)
typedef float f32x4 __attribute__((ext_vector_type(4)));
typedef float f32x16 __attribute__((ext_vector_type(16)));
typedef unsigned char u8;

__device__ __forceinline__ f32x16 mfma32(s16x8 a, s16x8 b, f32x16 c) {
    return __builtin_amdgcn_mfma_f32_32x32x16_bf16(a, b, c, 0, 0, 0);
}

__device__ __forceinline__ short f2bf(float f) {
    unsigned int u = __float_as_uint(f);
    u = (u + 0x7fffu + ((u >> 16) & 1u)) >> 16;
    return (short)u;
}

__device__ __forceinline__ unsigned cvt_pk(float lo, float hi) {
    unsigned r;
    asm("v_cvt_pk_bf16_f32 %0, %1, %2" : "=v"(r) : "v"(lo), "v"(hi));
    return r;
}

__device__ __forceinline__ void pl32swap(unsigned& a, unsigned& b) {
    asm("v_permlane32_swap_b32 %0, %1" : "+v"(a), "+v"(b));
}

__device__ __forceinline__ void gload_lds16(const void* g, void* l) {
    __builtin_amdgcn_global_load_lds(
        (const __attribute__((address_space(1))) unsigned int*)g,
        (__attribute__((address_space(3))) unsigned int*)l, 16, 0, 0);
}

#define BARRIER() __builtin_amdgcn_s_barrier()
#define LGKM0()   do { asm volatile("s_waitcnt lgkmcnt(0)" ::: "memory"); \
                       __builtin_amdgcn_sched_barrier(0); } while (0)

// ---------------------------------------------------------------------
// prep: W1^T / W2^T -> bf16 fragment-major for 32x32x16 MFMA.
//   w1t unit f = c*2048 + ct*1024 + s*64 + lane   (c<16, ct<2, s<16)
//     lane l holds W1[k = s*16 + (l>>5)*8 + j][n1 = c*64 + ct*32 + (l&31)]
//   w2t unit f = c*1024 + (ks*4+nt)*64 + lane     (c<16, ks<4, nt<4)
//     lane l holds W2[k2 = c*64 + ks*16 + (l>>5)*8 + j][n2 = nt*32 + (l&31)]
// ---------------------------------------------------------------------
__global__ __launch_bounds__(256) void prep_weights(
    const float* __restrict__ W1, const float* __restrict__ W2,
    uint4* __restrict__ w1t, uint4* __restrict__ w2t)
{
    int tid = blockIdx.x * 256 + threadIdx.x;
    int hl = (tid >> 5) & 1, r32 = tid & 31;
    union { short b[8]; uint4 v; } pk;
    if (tid < 32768) {                       // 32768 units = 512KB
        int s  = (tid >> 6) & 15;
        int ct = (tid >> 10) & 1;
        int c  = tid >> 11;
        int k0 = s * 16 + hl * 8;
        int n1 = c * 64 + ct * 32 + r32;
        #pragma unroll
        for (int j = 0; j < 8; ++j)
            pk.b[j] = f2bf(W1[(k0 + j) * 1024 + n1]);
        w1t[tid] = pk.v;
    } else {                                 // 16384 units = 256KB
        int g  = tid - 32768;
        int nt = (g >> 6) & 3;
        int ks = (g >> 8) & 3;
        int c  = g >> 10;
        int k0 = c * 64 + ks * 16 + hl * 8;
        int n2 = nt * 32 + r32;
        #pragma unroll
        for (int j = 0; j < 8; ++j)
            pk.b[j] = f2bf(W2[(k0 + j) * 128 + n2]);
        w2t[g] = pk.v;
    }
}

// ---------------------------------------------------------------------
// fused kernel. LDS: 3 x 48KB chunk buffers (32KB W1 + 16KB W2) + 4KB b1.
// ---------------------------------------------------------------------
__global__ __launch_bounds__(512, 1) void fused_all(
    const float* __restrict__ z, const float* __restrict__ b1,
    const float* __restrict__ b2, const uint4* __restrict__ w1t,
    const uint4* __restrict__ w2t, float* __restrict__ out)
{
    __shared__ __align__(16) u8 lds[151552];
    // buf k at k*49152: [0,32768) W1 chunk frags | [32768,49152) W2 frags
    // [147456,151552) b1 f32

    const int t    = threadIdx.x;
    const int lane = t & 63;
    const int w    = t >> 6;        // wave 0..7
    const int hl   = lane >> 5;
    const int r32  = lane & 31;
    const int bm0  = blockIdx.x * 256;
    const int rowbase = bm0 + w * 32;

    // ---------------- prologue staging: chunks 0 -> buf0, 1 -> buf1 -----
    #pragma unroll
    for (int i = 0; i < 4; ++i) {
        int f = i * 512 + t;
        gload_lds16(w1t + f, lds + f * 16);
        gload_lds16(w1t + 2048 + f, lds + 49152 + f * 16);
    }
    #pragma unroll
    for (int i = 0; i < 2; ++i) {
        int f = i * 512 + t;
        gload_lds16(w2t + f, lds + 32768 + f * 16);
        gload_lds16(w2t + 1024 + f, lds + 49152 + 32768 + f * 16);
    }
    if (t < 256) gload_lds16(b1 + t * 4, lds + 147456 + t * 16);

    // ---------------- eig (lanes 0..31: this wave's 32 rows) ------------
    if (lane < 32) {
        int row = rowbase + lane;
        const float* zr = z + (size_t)row * 256;
        float4 v0 = *(const float4*)(zr);
        float4 v1 = *(const float4*)(zr + 4);
        float2 v2 = *(const float2*)(zr + 8);

        float A[4][4] = {{v0.x, v0.y, v0.z, v0.w},
                         {v0.y, v1.x, v1.y, v1.z},
                         {v0.z, v1.y, v1.w, v2.x},
                         {v0.w, v1.z, v2.x, v2.y}};
        float V[4][4] = {{1.f, 0.f, 0.f, 0.f},
                         {0.f, 1.f, 0.f, 0.f},
                         {0.f, 0.f, 1.f, 0.f},
                         {0.f, 0.f, 0.f, 1.f}};

#define ROT(p, qq) do {                                                   \
        float apq  = A[p][qq];                                            \
        float tau  = (A[qq][qq] - A[p][p]) *                              \
                     __builtin_amdgcn_rcpf(2.0f * apq);                   \
        float tt   = __builtin_amdgcn_rcpf(                               \
                        fabsf(tau) +                                      \
                        __builtin_amdgcn_sqrtf(fmaf(tau, tau, 1.0f)));    \
        tt = copysignf(tt, tau);                                          \
        tt = (fabsf(apq) > 1e-20f) ? tt : 0.0f;                           \
        float cth = __builtin_amdgcn_rsqf(fmaf(tt, tt, 1.0f));            \
        float sth = tt * cth;                                             \
        _Pragma("unroll")                                                 \
        for (int k = 0; k < 4; ++k) {                                     \
            float akp = A[k][p], akq = A[k][qq];                          \
            A[k][p]  = cth * akp - sth * akq;                             \
            A[k][qq] = sth * akp + cth * akq;                             \
        }                                                                 \
        _Pragma("unroll")                                                 \
        for (int k = 0; k < 4; ++k) {                                     \
            float apk = A[p][k], aqk = A[qq][k];                          \
            A[p][k]  = cth * apk - sth * aqk;                             \
            A[qq][k] = sth * apk + cth * aqk;                             \
        }                                                                 \
        _Pragma("unroll")                                                 \
        for (int k = 0; k < 4; ++k) {                                     \
            float vkp = V[k][p], vkq = V[k][qq];                          \
            V[k][p]  = cth * vkp - sth * vkq;                             \
            V[k][qq] = sth * vkp + cth * vkq;                             \
        }                                                                 \
    } while (0)

        #pragma unroll 1
        for (int sweep = 0; sweep < 6; ++sweep) {
            ROT(0, 1); ROT(0, 2); ROT(0, 3); ROT(1, 2); ROT(1, 3); ROT(2, 3);
        }
#undef ROT

        float bv = A[0][0];
        float q0 = V[0][0], q1 = V[1][0], q2 = V[2][0], q3 = V[3][0];
        #pragma unroll
        for (int k = 1; k < 4; ++k) {
            bool better = A[k][k] > bv;
            bv = better ? A[k][k] : bv;
            q0 = better ? V[0][k] : q0;
            q1 = better ? V[1][k] : q1;
            q2 = better ? V[2][k] : q2;
            q3 = better ? V[3][k] : q3;
        }
        float sgn = (q0 + 1e-9f) >= 0.0f ? 1.0f : -1.0f;
        *(float4*)(out + (size_t)row * 132) =
            make_float4(sgn * q0, sgn * q1, sgn * q2, sgn * q3);
    }

    // ---------------- persistent z B-fragments ---------------------------
    s16x8 zf[16];
    {
        const float* zp = z + (size_t)(rowbase + r32) * 256 + hl * 8;
        #pragma unroll
        for (int s = 0; s < 16; ++s) {
            float4 a0 = *(const float4*)(zp + s * 16);
            float4 a1 = *(const float4*)(zp + s * 16 + 4);
            union { unsigned u[4]; s16x8 v; } pk;
            pk.u[0] = cvt_pk(a0.x, a0.y);
            pk.u[1] = cvt_pk(a0.z, a0.w);
            pk.u[2] = cvt_pk(a1.x, a1.y);
            pk.u[3] = cvt_pk(a1.z, a1.w);
            zf[s] = pk.v;
        }
    }

    const f32x16 zero16 = {0.f,0.f,0.f,0.f, 0.f,0.f,0.f,0.f,
                           0.f,0.f,0.f,0.f, 0.f,0.f,0.f,0.f};
    f32x16 acc2[4];
    #pragma unroll
    for (int nt = 0; nt < 4; ++nt) acc2[nt] = zero16;

    __syncthreads();   // prologue staging (chunks 0,1 + bias) landed

    const u8* const bufp0 = lds +          lane * 16;
    const u8* const bufp1 = lds + 49152  + lane * 16;
    const u8* const bufp2 = lds + 98304  + lane * 16;
    const u8* const blsp  = lds + 147456 + hl * 16;
    u8* const bufs0 = lds;
    u8* const bufs1 = lds + 49152;
    u8* const bufs2 = lds + 98304;

    s16x8 hf[4];

    // pack one GEMM1 D-tile -> 2 h fragments
    auto pack = [&](const f32x16& d, const u8* bb, int ct, s16x8* hfo) {
        unsigned Plo[4], Phi[4];
        #pragma unroll
        for (int g = 0; g < 4; ++g) {
            f32x4 bv = *(const f32x4*)(bb + ct * 128 + g * 32);
            Plo[g] = cvt_pk(fmaxf(d[4*g+0] + bv[0], 0.f),
                            fmaxf(d[4*g+1] + bv[1], 0.f));
            Phi[g] = cvt_pk(fmaxf(d[4*g+2] + bv[2], 0.f),
                            fmaxf(d[4*g+3] + bv[3], 0.f));
        }
        #pragma unroll
        for (int f = 0; f < 2; ++f) {
            unsigned a0 = Plo[2*f], b0 = Plo[2*f+1];
            unsigned a1 = Phi[2*f], b1_ = Phi[2*f+1];
            pl32swap(a0, b0);
            pl32swap(a1, b1_);
            union { unsigned u[4]; s16x8 v; } fr;
            fr.u[0] = a0; fr.u[1] = a1; fr.u[2] = b0; fr.u[3] = b1_;
            hfo[f] = fr.v;
        }
    };

    #pragma unroll
    for (int c = 0; c < 16; ++c) {
        const int ci = c % 3;
        const u8* a  = (ci == 0) ? bufp0 : (ci == 1) ? bufp1 : bufp2;
        const u8* wf = a + 32768;
        const int di = (c + 2) % 3;
        u8* dst = (di == 0) ? bufs0 : (di == 1) ? bufs1 : bufs2;
        const uint4* s1 = w1t + (c + 2) * 2048;
        const uint4* s2 = w2t + (c + 2) * 1024;
        const bool ST = (c <= 13);
        const u8* bb = blsp + c * 256;

        // ---- chunk-top counted vmcnt: chunk c's buffer (staged during
        // c-2) must be landed; chunk c-1's 6 loads stay IN FLIGHT.
        if (c >= 2) {
            if (c <= 14) asm volatile("s_waitcnt vmcnt(6)" ::: "memory");
            else         asm volatile("s_waitcnt vmcnt(0)" ::: "memory");
            __builtin_amdgcn_sched_barrier(0);
        }

        f32x16 d0 = zero16, d1 = zero16;

        // ================ P1: d0 s=0..7 | stage W1 half 1 ================
        {
            s16x8 af[8];
            #pragma unroll
            for (int s = 0; s < 8; ++s)
                af[s] = *(const s16x8*)(a + s * 1024);
            if (ST) {
                gload_lds16(s1 + t,       dst + t * 16);
                gload_lds16(s1 + 512 + t, dst + 8192 + t * 16);
            }
            BARRIER(); LGKM0();
            __builtin_amdgcn_s_setprio(1);
            #pragma unroll
            for (int s = 0; s < 8; ++s) d0 = mfma32(af[s], zf[s], d0);
            __builtin_amdgcn_s_setprio(0);
            BARRIER();
        }
        // ================ P2: d0 s=8..15 | stage W1 half 2 ===============
        {
            s16x8 af[8];
            #pragma unroll
            for (int s = 0; s < 8; ++s)
                af[s] = *(const s16x8*)(a + (8 + s) * 1024);
            if (ST) {
                gload_lds16(s1 + 1024 + t, dst + 16384 + t * 16);
                gload_lds16(s1 + 1536 + t, dst + 24576 + t * 16);
            }
            BARRIER(); LGKM0();
            __builtin_amdgcn_s_setprio(1);
            #pragma unroll
            for (int s = 0; s < 8; ++s) d0 = mfma32(af[s], zf[8 + s], d0);
            __builtin_amdgcn_s_setprio(0);
            BARRIER();
        }
        // ================ P3: d1 s=0..7 | stage W2 =======================
        {
            s16x8 af[8];
            #pragma unroll
            for (int s = 0; s < 8; ++s)
                af[s] = *(const s16x8*)(a + (16 + s) * 1024);
            if (ST) {
                gload_lds16(s2 + t,       dst + 32768 + t * 16);
                gload_lds16(s2 + 512 + t, dst + 40960 + t * 16);
            }
            BARRIER(); LGKM0();
            __builtin_amdgcn_s_setprio(1);
            #pragma unroll
            for (int s = 0; s < 8; ++s) d1 = mfma32(af[s], zf[s], d1);
            __builtin_amdgcn_s_setprio(0);
            BARRIER();
        }
        // ================ P4: d1 s=8..15 =================================
        {
            s16x8 af[8];
            #pragma unroll
            for (int s = 0; s < 8; ++s)
                af[s] = *(const s16x8*)(a + (24 + s) * 1024);
            BARRIER(); LGKM0();
            __builtin_amdgcn_s_setprio(1);
            #pragma unroll
            for (int s = 0; s < 8; ++s) d1 = mfma32(af[s], zf[8 + s], d1);
            __builtin_amdgcn_s_setprio(0);
            BARRIER();
        }
        // ================ P5: GEMM2 ks=0,1 | pack(d0) under ds_reads =====
        {
            s16x8 wfr[8];
            #pragma unroll
            for (int i = 0; i < 8; ++i)
                wfr[i] = *(const s16x8*)(wf + i * 1024);
            pack(d0, bb, 0, hf);          // VALU overlaps the 8 ds_reads
            BARRIER(); LGKM0();
            __builtin_amdgcn_s_setprio(1);
            #pragma unroll
            for (int ks = 0; ks < 2; ++ks)
                #pragma unroll
                for (int nt = 0; nt < 4; ++nt)
                    acc2[nt] = mfma32(hf[ks], wfr[ks * 4 + nt], acc2[nt]);
            __builtin_amdgcn_s_setprio(0);
            BARRIER();
        }
        // ================ P6: GEMM2 ks=2,3 | pack(d1) under ds_reads =====
        {
            s16x8 wfr[8];
            #pragma unroll
            for (int i = 0; i < 8; ++i)
                wfr[i] = *(const s16x8*)(wf + (8 + i) * 1024);
            pack(d1, bb, 1, hf + 2);
            BARRIER(); LGKM0();
            __builtin_amdgcn_s_setprio(1);
            #pragma unroll
            for (int ks = 0; ks < 2; ++ks)
                #pragma unroll
                for (int nt = 0; nt < 4; ++nt)
                    acc2[nt] = mfma32(hf[2 + ks], wfr[ks * 4 + nt], acc2[nt]);
            __builtin_amdgcn_s_setprio(0);
            BARRIER();
        }
    }

    // ---- epilogue: out[m][4 + n2] = acc2 + b2 ----
    #pragma unroll
    for (int nt = 0; nt < 4; ++nt) {
        const float b2v = b2[nt * 32 + r32];
        #pragma unroll
        for (int r = 0; r < 16; ++r) {
            int m = (r & 3) + 8 * (r >> 2) + 4 * hl;
            out[(size_t)(rowbase + m) * 132 + 4 + nt * 32 + r32] =
                acc2[nt][r] + b2v;
        }
    }
}

// ---------------------------------------------------------------------
extern "C" void kernel_launch(void* const* d_in, const int* in_sizes, int n_in,
                              void* d_out, int out_size, void* d_ws, size_t ws_size,
                              hipStream_t stream) {
    const float* z  = (const float*)d_in[0];
    const float* W1 = (const float*)d_in[1];
    const float* b1 = (const float*)d_in[2];
    const float* W2 = (const float*)d_in[3];
    const float* b2 = (const float*)d_in[4];
    float* out = (float*)d_out;

    uint4* w1t = (uint4*)d_ws;
    uint4* w2t = (uint4*)((char*)d_ws + 512 * 1024);

    hipLaunchKernelGGL(prep_weights, dim3(192), dim3(256), 0, stream,
                       W1, W2, w1t, w2t);
    hipLaunchKernelGGL(fused_all, dim3(256), dim3(512), 0, stream,
                       z, b1, b2, (const uint4*)w1t, (const uint4*)w2t, out);
}